// Round 3
// baseline (433.547 us; speedup 1.0000x reference)
//
#include <hip/hip_runtime.h>

// MeanAggregator: out[b,d] = mean_k table[neighs[b,k], d]
// B=50000, K=32, D=128, fp32 table/out, int32 idx.
//
// Windowed two-pass gather: pass 1 accumulates neighbors with row in
// [0, 250000), pass 2 rows in [250000, 500000). Each pass's random working
// set is ~123 MB -> resident in the 256 MB Infinity Cache, so the ~3.2x
// row reuse is served from L3 instead of HBM (round-1 measured 409 MB
// fetch vs 246 MB compulsory = ~50% reuse miss with the full 246 MB set).
// Partial sums round-trip through d_out (25.6 MB, L3-hot between passes).
// Out-of-window neighbors are redirected to row 0 (L1-hot) with weight 0
// so the 32 loads stay straight-line and batched (wave-uniform predicate,
// no divergence, no branches).

constexpr int BATCH     = 50000;
constexpr int DEGREE    = 32;
constexpr int D_FEAT    = 128;
constexpr int NUM_NODES = 500000;
constexpr int SPLIT     = NUM_NODES / 2;

typedef float f32x2 __attribute__((ext_vector_type(2)));

__global__ __launch_bounds__(256) void gather_window_kernel(
    const int* __restrict__ neighs,     // [B, K] int32
    const float* __restrict__ table,    // [N, D] fp32
    float* __restrict__ out,            // [B, D] fp32 (partial after pass 1)
    int lo, int hi, int final_pass)
{
    int node = blockIdx.x * 4 + (threadIdx.x >> 6);   // one wave per node
    node = __builtin_amdgcn_readfirstlane(node);      // force SGPR -> s_load idx
    const int lane = threadIdx.x & 63;

    const int* __restrict__ idx = neighs + (size_t)node * DEGREE;

    // Wave-uniform neighbor ids -> scalar registers.
    int rows[DEGREE];
#pragma unroll
    for (int k = 0; k < DEGREE; ++k) rows[k] = idx[k];

    // Window predicate (wave-uniform): out-of-window -> dummy row 0, weight 0.
    int   r[DEGREE];
    float w[DEGREE];
#pragma unroll
    for (int k = 0; k < DEGREE; ++k) {
        const bool in = (rows[k] >= lo) && (rows[k] < hi);
        r[k] = in ? rows[k] : 0;
        w[k] = in ? 1.0f : 0.0f;
    }

    // Batched row loads: lane L holds cols [2L, 2L+1]; 64 lanes x 8B = 512B
    // = one full row per wave-instruction. All 32 issued for MLP.
    float2 v[DEGREE];
#pragma unroll
    for (int k = 0; k < DEGREE; ++k)
        v[k] = reinterpret_cast<const float2*>(table + (size_t)r[k] * D_FEAT)[lane];

    float2 acc = make_float2(0.f, 0.f);
#pragma unroll
    for (int k = 0; k < DEGREE; ++k) {
        acc.x = fmaf(w[k], v[k].x, acc.x);
        acc.y = fmaf(w[k], v[k].y, acc.y);
    }

    f32x2* o = reinterpret_cast<f32x2*>(out + (size_t)node * D_FEAT) + lane;
    if (final_pass) {
        // Add pass-1 partial (L3-hot), scale, and stream out (never re-read).
        f32x2 prev = *o;
        f32x2 res;
        const float inv = 1.0f / (float)DEGREE;
        res.x = (acc.x + prev.x) * inv;
        res.y = (acc.y + prev.y) * inv;
        __builtin_nontemporal_store(res, o);
    } else {
        // Raw partial sum; keep it cache-resident for pass 2's read.
        f32x2 p; p.x = acc.x; p.y = acc.y;
        *o = p;
    }
}

extern "C" void kernel_launch(void* const* d_in, const int* in_sizes, int n_in,
                              void* d_out, int out_size, void* d_ws, size_t ws_size,
                              hipStream_t stream) {
    const int*   neighs = (const int*)d_in[0];
    const float* table  = (const float*)d_in[1];
    float*       out    = (float*)d_out;

    const int grid = BATCH / 4;   // 4 waves (nodes) per 256-thread block
    gather_window_kernel<<<grid, 256, 0, stream>>>(neighs, table, out,
                                                   0, SPLIT, 0);
    gather_window_kernel<<<grid, 256, 0, stream>>>(neighs, table, out,
                                                   SPLIT, NUM_NODES, 1);
}

// Round 4
// 399.241 us; speedup vs baseline: 1.0859x; 1.0859x over previous
//
#include <hip/hip_runtime.h>

// MeanAggregator: out[b,d] = mean_k table[neighs[b,k], d]
// B=50000, K=32, D=128, fp32 table/out, int32 idx.
//
// R4 theory: round-1 (152 us, 2.86 TB/s, VGPR=24) was latency*concurrency
// bound, not byte bound (round-3 cut HBM bytes and got SLOWER). Fix the
// concurrency: two nodes per wave (half-wave each), 16 B/lane dwordx4 loads
// (1 KB = 2 rows per instruction), explicit double-buffered register
// pipeline with 8 loads per group so ~16 KB/wave is in flight. Indices come
// in via one coalesced per-lane load + __shfl broadcast (no scalar-load
// serialization).

constexpr int BATCH  = 50000;
constexpr int DEGREE = 32;
constexpr int D_FEAT = 128;

typedef float f32x4 __attribute__((ext_vector_type(4)));

__global__ __launch_bounds__(256) void MeanAggregator_841813590039_kernel(
    const int* __restrict__ neighs,     // [B, K] int32
    const float* __restrict__ table,    // [N, D] fp32
    float* __restrict__ out)            // [B, D] fp32
{
    const int wave  = (blockIdx.x * 256 + threadIdx.x) >> 6;  // global wave id
    const int lane  = threadIdx.x & 63;
    const int nodeA = wave * 2;                // lanes 0-31: nodeA, 32-63: nodeA+1
    const int col   = lane & 31;               // float4 column group (16B each)
    const int half  = lane & 32;               // 0 or 32: selects my node's indices

    // All 64 neighbor ids for both nodes in one coalesced load (4B/lane).
    const int rows = neighs[(size_t)nodeA * DEGREE + lane];

    // k-th neighbor row for MY half-wave: broadcast from lane (half + k).
    #define ROW(k) __shfl(rows, half + (k), 64)
    #define LOADK(k) \
        reinterpret_cast<const f32x4*>(table + (size_t)ROW(k) * D_FEAT)[col]

    f32x4 buf0[8], buf1[8];

    // Prologue: issue group 0.
    #pragma unroll
    for (int j = 0; j < 8; ++j) buf0[j] = LOADK(j);

    f32x4 acc = {0.f, 0.f, 0.f, 0.f};

    // Steady state: issue group g+1, then consume group g.
    #pragma unroll
    for (int g = 0; g < 3; ++g) {
        f32x4* cur = (g & 1) ? buf1 : buf0;
        f32x4* nxt = (g & 1) ? buf0 : buf1;
        #pragma unroll
        for (int j = 0; j < 8; ++j) nxt[j] = LOADK((g + 1) * 8 + j);
        #pragma unroll
        for (int j = 0; j < 8; ++j) acc += cur[j];
    }
    // Epilogue: consume group 3 (lives in buf1 after g=2).
    #pragma unroll
    for (int j = 0; j < 8; ++j) acc += buf1[j];

    #undef LOADK
    #undef ROW

    const float inv = 1.0f / (float)DEGREE;
    acc *= inv;

    // Lane L writes cols [4*col .. 4*col+3] of its node: two contiguous
    // 512B segments per wave, fully coalesced. Never re-read -> nontemporal.
    const int node = nodeA + (half >> 5);
    f32x4* o = reinterpret_cast<f32x4*>(out + (size_t)node * D_FEAT) + col;
    __builtin_nontemporal_store(acc, o);
}

extern "C" void kernel_launch(void* const* d_in, const int* in_sizes, int n_in,
                              void* d_out, int out_size, void* d_ws, size_t ws_size,
                              hipStream_t stream) {
    const int*   neighs = (const int*)d_in[0];
    const float* table  = (const float*)d_in[1];
    float*       out    = (float*)d_out;

    // 2 nodes per wave, 4 waves per block -> 8 nodes per block.
    const int grid = BATCH / 8;   // 6250, exact
    MeanAggregator_841813590039_kernel<<<grid, 256, 0, stream>>>(neighs, table, out);
}